// Round 3
// baseline (262.369 us; speedup 1.0000x reference)
//
#include <hip/hip_runtime.h>
#include <math.h>

#define CCH   256
#define NPIX  4096
#define BATCH 4

typedef __attribute__((ext_vector_type(8))) short s16x8;
typedef __attribute__((ext_vector_type(4))) float f32x4;

__device__ __forceinline__ unsigned short f2bf(float f) {
    unsigned int u = __float_as_uint(f);
    u += 0x7fff + ((u >> 16) & 1);          // RNE; values are finite
    return (unsigned short)(u >> 16);
}
__device__ __forceinline__ float bf2f(unsigned short h) {
    return __uint_as_float(((unsigned int)h) << 16);
}

// q/k frag (16x16x32 A/B layout): element for (pixel n, dim d):
//   lane = (d>>3)*16 + (n&15), elem = d&7, tile = n>>4
__device__ __forceinline__ size_t qk_addr(int b, int n, int d) {
    return ((((size_t)b * 256 + (n >> 4)) * 64 + ((d >> 3) << 4) + (n & 15)) << 3) + (d & 7);
}
// v frag: A-operand of PV (V^T), j->k mapping: k=quad*8+dd <-> j=(2h+(dd>>2))*16+quad*4+(dd&3)
__device__ __forceinline__ size_t v_addr(int b, int j, int c) {
    return ((((((size_t)b * 64 + (j >> 6)) * 16 + (c >> 4)) * 2 + ((j >> 5) & 1)) * 64
            + ((j >> 2) & 3) * 16 + (c & 15)) << 3) + ((j >> 4) & 1) * 4 + (j & 3);
}

// ---------------- x -> bf16 hi/lo, swizzled B-frag layout ----------------
__global__ __launch_bounds__(256) void cast_kernel(
    const float* __restrict__ x,
    unsigned short* __restrict__ x_hi, unsigned short* __restrict__ x_lo)
{
    const int t = threadIdx.x, w = t >> 6, lane = t & 63, l15 = lane & 15, quad = lane >> 4;
    const int b = blockIdx.y;
    const int nt = blockIdx.x * 4 + w;
    const float* xb = x + (size_t)b * CCH * NPIX + nt * 16 + l15;
    const size_t base = (((size_t)b * 256 + nt) * 8) * 512 + (size_t)lane * 8;
    #pragma unroll 1
    for (int kb = 0; kb < 8; ++kb) {
        s16x8 vh, vl;
        #pragma unroll
        for (int d = 0; d < 8; ++d) {
            float xv = xb[(size_t)(kb * 32 + quad * 8 + d) * NPIX];
            unsigned short h = f2bf(xv);
            vh[d] = (short)h;
            vl[d] = (short)f2bf(xv - bf2f(h));
        }
        *(s16x8*)(x_hi + base + kb * 512) = vh;
        *(s16x8*)(x_lo + base + kb * 512) = vl;
    }
}

// ---------------- projections via MFMA; q/k in hi/lo (3-term), v plain ----------------
__global__ __launch_bounds__(256) void proj_kernel(
    const unsigned short* __restrict__ x_hi, const unsigned short* __restrict__ x_lo,
    const float* __restrict__ Wq, const float* __restrict__ bq,
    const float* __restrict__ Wk, const float* __restrict__ bk,
    const float* __restrict__ Wv, const float* __restrict__ bv,
    unsigned short* __restrict__ q_hi, unsigned short* __restrict__ q_lo,
    unsigned short* __restrict__ k_hi, unsigned short* __restrict__ k_lo,
    unsigned short* __restrict__ v_frag)
{
    const int t = threadIdx.x;
    const int w = t >> 6, lane = t & 63, l15 = lane & 15, quad = lane >> 4;
    const int b = blockIdx.z, rg = blockIdx.y;
    const int n0 = blockIdx.x * 128;
    const int rbase = rg * 64 + w * 16;

    const float *Ws, *bs; int roff, mode;       // 0=q (pre-scaled by log2e), 1=k, 2=v
    if (rbase < 32)      { Ws = Wq; bs = bq; roff = rbase;      mode = 0; }
    else if (rbase < 64) { Ws = Wk; bs = bk; roff = rbase - 32; mode = 1; }
    else                 { Ws = Wv; bs = bv; roff = rbase - 64; mode = 2; }
    const float scale = (mode == 0) ? 1.44269504f : 1.0f;

    s16x8 af_h[8], af_l[8];
    const float* wrow = Ws + (size_t)(roff + l15) * CCH + quad * 8;
    #pragma unroll
    for (int kb = 0; kb < 8; ++kb) {
        s16x8 ah, al;
        #pragma unroll
        for (int d = 0; d < 8; ++d) {
            float wv = wrow[kb * 32 + d] * scale;
            unsigned short h = f2bf(wv);
            ah[d] = (short)h;
            al[d] = (short)f2bf(wv - bf2f(h));
        }
        af_h[kb] = ah; af_l[kb] = al;
    }
    float bias[4];
    #pragma unroll
    for (int rr = 0; rr < 4; ++rr) bias[rr] = bs[roff + quad * 4 + rr] * scale;

    #pragma unroll 1
    for (int nt = 0; nt < 8; ++nt) {
        const int ntg = (n0 >> 4) + nt;
        const size_t xbase = (((size_t)b * 256 + ntg) * 8) * 512 + (size_t)lane * 8;
        f32x4 acc = {0.f, 0.f, 0.f, 0.f};
        if (mode == 2) {
            #pragma unroll
            for (int kb = 0; kb < 8; ++kb) {
                s16x8 bh = *(const s16x8*)(x_hi + xbase + kb * 512);
                acc = __builtin_amdgcn_mfma_f32_16x16x32_bf16(af_h[kb], bh, acc, 0, 0, 0);
            }
        } else {
            #pragma unroll
            for (int kb = 0; kb < 8; ++kb) {
                s16x8 bh = *(const s16x8*)(x_hi + xbase + kb * 512);
                s16x8 bl = *(const s16x8*)(x_lo + xbase + kb * 512);
                acc = __builtin_amdgcn_mfma_f32_16x16x32_bf16(af_h[kb], bl, acc, 0, 0, 0);
                acc = __builtin_amdgcn_mfma_f32_16x16x32_bf16(af_l[kb], bh, acc, 0, 0, 0);
                acc = __builtin_amdgcn_mfma_f32_16x16x32_bf16(af_h[kb], bh, acc, 0, 0, 0);
            }
        }
        const int n = n0 + nt * 16 + l15;
        #pragma unroll
        for (int rr = 0; rr < 4; ++rr) {
            const int r = roff + quad * 4 + rr;
            const float val = acc[rr] + bias[rr];
            if (mode == 2) {
                v_frag[v_addr(b, n, r)] = f2bf(val);
            } else {
                unsigned short h = f2bf(val);
                unsigned short l = f2bf(val - bf2f(h));
                const size_t a = qk_addr(b, n, r);
                if (mode == 0) { q_hi[a] = h; q_lo[a] = l; }
                else           { k_hi[a] = h; k_lo[a] = l; }
            }
        }
    }
}

// ---------------- flash attention: static softmax, S^T trick, no LDS ----------------
// 512 threads = 8 waves: wave = (row-tile r 0..3, channel-half ch 0..1).
// All waves walk the same KV tiles -> L1 dedupes V/K. No barriers needed (soft sync).
__global__ __launch_bounds__(512) void attn_kernel(
    const unsigned short* __restrict__ q_hi, const unsigned short* __restrict__ q_lo,
    const unsigned short* __restrict__ k_hi, const unsigned short* __restrict__ k_lo,
    const unsigned short* __restrict__ v_frag,
    const float* __restrict__ x, float* __restrict__ out)
{
    const int t = threadIdx.x;
    const int w = t >> 6, lane = t & 63, l15 = lane & 15, quad = lane >> 4;
    const int r = w >> 1, ch = w & 1;
    const int b = blockIdx.y;
    const int it = blockIdx.x * 4 + r;
    const int i0 = it * 16;

    const size_t qoff = ((size_t)b * 256 + it) * 512 + (size_t)lane * 8;
    const s16x8 qh = *(const s16x8*)(q_hi + qoff);
    const s16x8 ql = *(const s16x8*)(q_lo + qoff);

    f32x4 acc[8];
    #pragma unroll
    for (int i = 0; i < 8; ++i) acc[i] = (f32x4){0.f, 0.f, 0.f, 0.f};
    float l_acc = 0.f;

    const unsigned short* khb = k_hi + (size_t)b * 131072 + (size_t)lane * 8;
    const unsigned short* klb = k_lo + (size_t)b * 131072 + (size_t)lane * 8;
    const unsigned short* vb  = v_frag + (size_t)b * 1048576 + (size_t)lane * 8;

    #pragma unroll 1
    for (int jt = 0; jt < 64; ++jt) {
        // ---- S^T = K (Q log2e)^T : 12 MFMAs (hi/lo 3-term) ----
        f32x4 s[4];
        #pragma unroll
        for (int ct = 0; ct < 4; ++ct) {
            const size_t ko = (size_t)(jt * 4 + ct) * 512;
            s16x8 kh = *(const s16x8*)(khb + ko);
            s16x8 kl = *(const s16x8*)(klb + ko);
            f32x4 a0 = __builtin_amdgcn_mfma_f32_16x16x32_bf16(kh, ql, (f32x4){0.f,0.f,0.f,0.f}, 0, 0, 0);
            a0 = __builtin_amdgcn_mfma_f32_16x16x32_bf16(kl, qh, a0, 0, 0, 0);
            a0 = __builtin_amdgcn_mfma_f32_16x16x32_bf16(kh, qh, a0, 0, 0, 0);
            s[ct] = a0;
        }
        // ---- static softmax numerators + running denominator ----
        unsigned int dw[8];
        #pragma unroll
        for (int ct = 0; ct < 4; ++ct) {
            float p0 = __builtin_exp2f(s[ct][0]);
            float p1 = __builtin_exp2f(s[ct][1]);
            float p2 = __builtin_exp2f(s[ct][2]);
            float p3 = __builtin_exp2f(s[ct][3]);
            l_acc += (p0 + p1) + (p2 + p3);
            dw[ct * 2 + 0] = (unsigned int)f2bf(p0) | ((unsigned int)f2bf(p1) << 16);
            dw[ct * 2 + 1] = (unsigned int)f2bf(p2) | ((unsigned int)f2bf(p3) << 16);
        }
        // C-layout of S^T == B-operand layout of P for PV (by construction): pure repack
        union { unsigned int u[4]; s16x8 v; } pu0, pu1;
        pu0.u[0] = dw[0]; pu0.u[1] = dw[1]; pu0.u[2] = dw[2]; pu0.u[3] = dw[3];
        pu1.u[0] = dw[4]; pu1.u[1] = dw[5]; pu1.u[2] = dw[6]; pu1.u[3] = dw[7];
        // ---- PV: out^T[c][i] += V^T P^T, 16 MFMAs over this wave's 128 channels ----
        #pragma unroll
        for (int c2 = 0; c2 < 8; ++c2) {
            const int ct2g = ch * 8 + c2;
            const size_t vo = (size_t)jt * 16384 + (size_t)ct2g * 1024;
            s16x8 v0 = *(const s16x8*)(vb + vo);
            s16x8 v1 = *(const s16x8*)(vb + vo + 512);
            acc[c2] = __builtin_amdgcn_mfma_f32_16x16x32_bf16(v0, pu0.v, acc[c2], 0, 0, 0);
            acc[c2] = __builtin_amdgcn_mfma_f32_16x16x32_bf16(v1, pu1.v, acc[c2], 0, 0, 0);
        }
        if ((jt & 15) == 15) __syncthreads();   // keep waves clustered for L1 reuse
    }

    // ---- epilogue: reduce l over quads, normalize, residual, store ----
    l_acc += __shfl_xor(l_acc, 16);
    l_acc += __shfl_xor(l_acc, 32);
    const float linv = 1.f / l_acc;             // l for column i = l15
    #pragma unroll
    for (int c2 = 0; c2 < 8; ++c2) {
        const int cb = ch * 128 + c2 * 16 + quad * 4;
        #pragma unroll
        for (int rr = 0; rr < 4; ++rr) {
            const size_t idx = ((size_t)b * CCH + cb + rr) * NPIX + i0 + l15;
            out[idx] = acc[c2][rr] * linv + x[idx];
        }
    }
}

extern "C" void kernel_launch(void* const* d_in, const int* in_sizes, int n_in,
                              void* d_out, int out_size, void* d_ws, size_t ws_size,
                              hipStream_t stream) {
    const float* x  = (const float*)d_in[0];
    const float* Wq = (const float*)d_in[1];
    const float* bq = (const float*)d_in[2];
    const float* Wk = (const float*)d_in[3];
    const float* bk = (const float*)d_in[4];
    const float* Wv = (const float*)d_in[5];
    const float* bv = (const float*)d_in[6];
    float* out = (float*)d_out;

    unsigned short* ws = (unsigned short*)d_ws;
    unsigned short* x_hi   = ws;                 // 4,194,304
    unsigned short* x_lo   = ws + 4194304;       // 4,194,304
    unsigned short* q_hi   = ws + 8388608;       //   524,288
    unsigned short* q_lo   = ws + 8912896;       //   524,288
    unsigned short* k_hi   = ws + 9437184;       //   524,288
    unsigned short* k_lo   = ws + 9961472;       //   524,288
    unsigned short* v_frag = ws + 10485760;      // 4,194,304  -> ~28 MB total

    cast_kernel<<<dim3(64, BATCH), 256, 0, stream>>>(x, x_hi, x_lo);
    proj_kernel<<<dim3(32, 5, BATCH), 256, 0, stream>>>(x_hi, x_lo, Wq, bq, Wk, bk, Wv, bv,
                                                        q_hi, q_lo, k_hi, k_lo, v_frag);
    attn_kernel<<<dim3(64, BATCH), 512, 0, stream>>>(q_hi, q_lo, k_hi, k_lo, v_frag, x, out);
}

// Round 4
// 216.043 us; speedup vs baseline: 1.2144x; 1.2144x over previous
//
#include <hip/hip_runtime.h>
#include <math.h>

#define CCH   256
#define NPIX  4096
#define BATCH 4

typedef __attribute__((ext_vector_type(8))) short s16x8;
typedef __attribute__((ext_vector_type(4))) float f32x4;

__device__ __forceinline__ unsigned short f2bf(float f) {
    unsigned int u = __float_as_uint(f);
    u += 0x7fff + ((u >> 16) & 1);          // RNE; values are finite
    return (unsigned short)(u >> 16);
}
__device__ __forceinline__ float bf2f(unsigned short h) {
    return __uint_as_float(((unsigned int)h) << 16);
}

// q/k frag (16x16x32 A/B layout): element for (pixel n, dim d):
//   lane = (d>>3)*16 + (n&15), elem = d&7, tile = n>>4
__device__ __forceinline__ size_t qk_addr(int b, int n, int d) {
    return ((((size_t)b * 256 + (n >> 4)) * 64 + ((d >> 3) << 4) + (n & 15)) << 3) + (d & 7);
}
// v frag: A-operand of PV (V^T), j->k mapping: k=quad*8+dd <-> j=(2h+(dd>>2))*16+quad*4+(dd&3)
__device__ __forceinline__ size_t v_addr(int b, int j, int c) {
    return ((((((size_t)b * 64 + (j >> 6)) * 16 + (c >> 4)) * 2 + ((j >> 5) & 1)) * 64
            + ((j >> 2) & 3) * 16 + (c & 15)) << 3) + ((j >> 4) & 1) * 4 + (j & 3);
}

// ---------------- x -> bf16 hi/lo, swizzled B-frag layout ----------------
// One block per i-tile: 1024 blocks, 4 waves each (kb pair per wave).
__global__ __launch_bounds__(256) void cast_kernel(
    const float* __restrict__ x,
    unsigned short* __restrict__ x_hi, unsigned short* __restrict__ x_lo)
{
    const int t = threadIdx.x, w = t >> 6, lane = t & 63, l15 = lane & 15, quad = lane >> 4;
    const int b = blockIdx.y;
    const int nt = blockIdx.x;
    const float* xb = x + (size_t)b * CCH * NPIX + nt * 16 + l15;
    const size_t base = (((size_t)b * 256 + nt) * 8) * 512 + (size_t)lane * 8;
    #pragma unroll
    for (int kk = 0; kk < 2; ++kk) {
        const int kb = w * 2 + kk;
        s16x8 vh, vl;
        #pragma unroll
        for (int d = 0; d < 8; ++d) {
            float xv = xb[(size_t)(kb * 32 + quad * 8 + d) * NPIX];
            unsigned short h = f2bf(xv);
            vh[d] = (short)h;
            vl[d] = (short)f2bf(xv - bf2f(h));
        }
        *(s16x8*)(x_hi + base + kb * 512) = vh;
        *(s16x8*)(x_lo + base + kb * 512) = vl;
    }
}

// ---------------- projections via MFMA; q/k in hi/lo (3-term), v plain ----------------
__global__ __launch_bounds__(256) void proj_kernel(
    const unsigned short* __restrict__ x_hi, const unsigned short* __restrict__ x_lo,
    const float* __restrict__ Wq, const float* __restrict__ bq,
    const float* __restrict__ Wk, const float* __restrict__ bk,
    const float* __restrict__ Wv, const float* __restrict__ bv,
    unsigned short* __restrict__ q_hi, unsigned short* __restrict__ q_lo,
    unsigned short* __restrict__ k_hi, unsigned short* __restrict__ k_lo,
    unsigned short* __restrict__ v_frag)
{
    const int t = threadIdx.x;
    const int w = t >> 6, lane = t & 63, l15 = lane & 15, quad = lane >> 4;
    const int b = blockIdx.z, rg = blockIdx.y;
    const int n0 = blockIdx.x * 64;
    const int rbase = rg * 64 + w * 16;

    const float *Ws, *bs; int roff, mode;       // 0=q (pre-scaled by log2e), 1=k, 2=v
    if (rbase < 32)      { Ws = Wq; bs = bq; roff = rbase;      mode = 0; }
    else if (rbase < 64) { Ws = Wk; bs = bk; roff = rbase - 32; mode = 1; }
    else                 { Ws = Wv; bs = bv; roff = rbase - 64; mode = 2; }
    const float scale = (mode == 0) ? 1.44269504f : 1.0f;

    s16x8 af_h[8], af_l[8];
    const float* wrow = Ws + (size_t)(roff + l15) * CCH + quad * 8;
    #pragma unroll
    for (int kb = 0; kb < 8; ++kb) {
        s16x8 ah, al;
        #pragma unroll
        for (int d = 0; d < 8; ++d) {
            float wv = wrow[kb * 32 + d] * scale;
            unsigned short h = f2bf(wv);
            ah[d] = (short)h;
            al[d] = (short)f2bf(wv - bf2f(h));
        }
        af_h[kb] = ah; af_l[kb] = al;
    }
    float bias[4];
    #pragma unroll
    for (int rr = 0; rr < 4; ++rr) bias[rr] = bs[roff + quad * 4 + rr] * scale;

    #pragma unroll 1
    for (int nt = 0; nt < 4; ++nt) {
        const int ntg = (n0 >> 4) + nt;
        const size_t xbase = (((size_t)b * 256 + ntg) * 8) * 512 + (size_t)lane * 8;
        f32x4 acc = {0.f, 0.f, 0.f, 0.f};
        if (mode == 2) {
            #pragma unroll
            for (int kb = 0; kb < 8; ++kb) {
                s16x8 bh = *(const s16x8*)(x_hi + xbase + kb * 512);
                acc = __builtin_amdgcn_mfma_f32_16x16x32_bf16(af_h[kb], bh, acc, 0, 0, 0);
            }
        } else {
            #pragma unroll
            for (int kb = 0; kb < 8; ++kb) {
                s16x8 bh = *(const s16x8*)(x_hi + xbase + kb * 512);
                s16x8 bl = *(const s16x8*)(x_lo + xbase + kb * 512);
                acc = __builtin_amdgcn_mfma_f32_16x16x32_bf16(af_h[kb], bl, acc, 0, 0, 0);
                acc = __builtin_amdgcn_mfma_f32_16x16x32_bf16(af_l[kb], bh, acc, 0, 0, 0);
                acc = __builtin_amdgcn_mfma_f32_16x16x32_bf16(af_h[kb], bh, acc, 0, 0, 0);
            }
        }
        const int n = n0 + nt * 16 + l15;
        #pragma unroll
        for (int rr = 0; rr < 4; ++rr) {
            const int r = roff + quad * 4 + rr;
            const float val = acc[rr] + bias[rr];
            if (mode == 2) {
                v_frag[v_addr(b, n, r)] = f2bf(val);
            } else {
                unsigned short h = f2bf(val);
                unsigned short l = f2bf(val - bf2f(h));
                const size_t a = qk_addr(b, n, r);
                if (mode == 0) { q_hi[a] = h; q_lo[a] = l; }
                else           { k_hi[a] = h; k_lo[a] = l; }
            }
        }
    }
}

// ---------------- flash attention: static softmax, S^T trick, KV-split ----------------
// 1024 threads = 16 waves: (jh 0..3) x (ch 0..1) x (r 0..1). Each wave: 16 KV tiles,
// one i-tile (it = bx*2+r), 128 channels. Epilogue combines jh partials via LDS.
__global__ __launch_bounds__(1024, 4) void attn_kernel(
    const unsigned short* __restrict__ q_hi, const unsigned short* __restrict__ q_lo,
    const unsigned short* __restrict__ k_hi, const unsigned short* __restrict__ k_lo,
    const unsigned short* __restrict__ v_frag,
    const float* __restrict__ x, float* __restrict__ out)
{
    __shared__ float lds_acc[8][64][36];   // [region][lane][c2*4+rr], stride 36 (16B-aligned)
    __shared__ float lds_l[8][16];

    const int t = threadIdx.x;
    const int w = t >> 6, lane = t & 63, l15 = lane & 15, quad = lane >> 4;
    const int jh = w >> 2;            // KV quarter
    const int ch = (w >> 1) & 1;      // channel half
    const int r  = w & 1;             // row-tile within block

    // XCD-aware swizzle: batch b lives on XCD pair {2b, 2b+1}
    const int f = blockIdx.x + gridDim.x * blockIdx.y;   // 0..511
    const int xcd = f & 7;
    const int b = xcd >> 1;
    const int it = (((xcd & 1) << 6) + (f >> 3)) * 2 + r;
    const int i0 = it * 16;

    const size_t qoff = ((size_t)b * 256 + it) * 512 + (size_t)lane * 8;
    const s16x8 qh = *(const s16x8*)(q_hi + qoff);
    const s16x8 ql = *(const s16x8*)(q_lo + qoff);

    const s16x8 ones = { (short)0x3F80, (short)0x3F80, (short)0x3F80, (short)0x3F80,
                         (short)0x3F80, (short)0x3F80, (short)0x3F80, (short)0x3F80 };

    f32x4 acc[8];
    #pragma unroll
    for (int i = 0; i < 8; ++i) acc[i] = (f32x4){0.f, 0.f, 0.f, 0.f};
    f32x4 lacc = {0.f, 0.f, 0.f, 0.f};

    const unsigned short* khb = k_hi + (size_t)b * 131072 + (size_t)lane * 8;
    const unsigned short* klb = k_lo + (size_t)b * 131072 + (size_t)lane * 8;
    const unsigned short* vb  = v_frag + (size_t)b * 1048576 + (size_t)lane * 8;

    #pragma unroll 1
    for (int j5 = 0; j5 < 16; ++j5) {
        const int jt = jh * 16 + j5;
        // ---- S^T = K (Q log2e)^T : 12 MFMAs (hi/lo 3-term) ----
        f32x4 s[4];
        #pragma unroll
        for (int ct = 0; ct < 4; ++ct) {
            const size_t ko = (size_t)(jt * 4 + ct) * 512;
            s16x8 kh = *(const s16x8*)(khb + ko);
            s16x8 kl = *(const s16x8*)(klb + ko);
            f32x4 a0 = __builtin_amdgcn_mfma_f32_16x16x32_bf16(kh, ql, (f32x4){0.f,0.f,0.f,0.f}, 0, 0, 0);
            a0 = __builtin_amdgcn_mfma_f32_16x16x32_bf16(kl, qh, a0, 0, 0, 0);
            a0 = __builtin_amdgcn_mfma_f32_16x16x32_bf16(kh, qh, a0, 0, 0, 0);
            s[ct] = a0;
        }
        // ---- exp2 + pack (half-up round via +0x8000, v_perm pair-pack) ----
        unsigned int dw[8];
        #pragma unroll
        for (int ct = 0; ct < 4; ++ct) {
            unsigned int u0 = __float_as_uint(__builtin_exp2f(s[ct][0])) + 0x8000u;
            unsigned int u1 = __float_as_uint(__builtin_exp2f(s[ct][1])) + 0x8000u;
            unsigned int u2 = __float_as_uint(__builtin_exp2f(s[ct][2])) + 0x8000u;
            unsigned int u3 = __float_as_uint(__builtin_exp2f(s[ct][3])) + 0x8000u;
            dw[ct * 2 + 0] = __builtin_amdgcn_perm(u1, u0, 0x07060302u);
            dw[ct * 2 + 1] = __builtin_amdgcn_perm(u3, u2, 0x07060302u);
        }
        union { unsigned int u[4]; s16x8 v; } pu0, pu1;
        pu0.u[0] = dw[0]; pu0.u[1] = dw[1]; pu0.u[2] = dw[2]; pu0.u[3] = dw[3];
        pu1.u[0] = dw[4]; pu1.u[1] = dw[5]; pu1.u[2] = dw[6]; pu1.u[3] = dw[7];
        // ---- denominator via ones-MFMA: lacc[*][i] += sum_j P[j][i] ----
        lacc = __builtin_amdgcn_mfma_f32_16x16x32_bf16(ones, pu0.v, lacc, 0, 0, 0);
        lacc = __builtin_amdgcn_mfma_f32_16x16x32_bf16(ones, pu1.v, lacc, 0, 0, 0);
        // ---- PV: 16 MFMAs over this wave's 128 channels ----
        #pragma unroll
        for (int c2 = 0; c2 < 8; ++c2) {
            const size_t vo = (size_t)jt * 16384 + (size_t)(ch * 8 + c2) * 1024;
            s16x8 v0 = *(const s16x8*)(vb + vo);
            s16x8 v1 = *(const s16x8*)(vb + vo + 512);
            acc[c2] = __builtin_amdgcn_mfma_f32_16x16x32_bf16(v0, pu0.v, acc[c2], 0, 0, 0);
            acc[c2] = __builtin_amdgcn_mfma_f32_16x16x32_bf16(v1, pu1.v, acc[c2], 0, 0, 0);
        }
        if ((j5 & 7) == 7) __syncthreads();   // keep r-partners clustered for L1 V dedupe
    }

    // ---- combine jh partials via LDS tree ----
    const int rc = r * 2 + ch;                // region group 0..3
    float lsum = lacc[0];                     // uniform over quad/rr; indexed by i=l15

    // Phase A: jh in {1,3} publish
    if (jh & 1) {
        const int reg = rc * 2 + (jh >> 1);
        #pragma unroll
        for (int c2 = 0; c2 < 8; ++c2)
            *(f32x4*)&lds_acc[reg][lane][c2 * 4] = acc[c2];
        if (lane < 16) lds_l[reg][lane] = lsum;
    }
    __syncthreads();
    // Phase B: jh0 += jh1 ; jh2 += jh3 then republish
    if (jh == 0) {
        const int reg = rc * 2;
        #pragma unroll
        for (int c2 = 0; c2 < 8; ++c2)
            acc[c2] += *(const f32x4*)&lds_acc[reg][lane][c2 * 4];
        lsum += lds_l[reg][l15];
    } else if (jh == 2) {
        const int reg = rc * 2 + 1;
        #pragma unroll
        for (int c2 = 0; c2 < 8; ++c2)
            acc[c2] += *(const f32x4*)&lds_acc[reg][lane][c2 * 4];
        lsum += lds_l[reg][l15];
        #pragma unroll
        for (int c2 = 0; c2 < 8; ++c2)
            *(f32x4*)&lds_acc[reg][lane][c2 * 4] = acc[c2];
        if (lane < 16) lds_l[reg][lane] = lsum;
    }
    __syncthreads();
    // Phase C: jh0 += (jh2+jh3), normalize, residual, store
    if (jh == 0) {
        const int reg = rc * 2 + 1;
        #pragma unroll
        for (int c2 = 0; c2 < 8; ++c2)
            acc[c2] += *(const f32x4*)&lds_acc[reg][lane][c2 * 4];
        lsum += lds_l[reg][l15];
        const float linv = 1.f / lsum;
        #pragma unroll
        for (int c2 = 0; c2 < 8; ++c2) {
            const int cb = ch * 128 + c2 * 16 + quad * 4;
            #pragma unroll
            for (int rr = 0; rr < 4; ++rr) {
                const size_t idx = ((size_t)b * CCH + cb + rr) * NPIX + i0 + l15;
                out[idx] = acc[c2][rr] * linv + x[idx];
            }
        }
    }
}

extern "C" void kernel_launch(void* const* d_in, const int* in_sizes, int n_in,
                              void* d_out, int out_size, void* d_ws, size_t ws_size,
                              hipStream_t stream) {
    const float* x  = (const float*)d_in[0];
    const float* Wq = (const float*)d_in[1];
    const float* bq = (const float*)d_in[2];
    const float* Wk = (const float*)d_in[3];
    const float* bk = (const float*)d_in[4];
    const float* Wv = (const float*)d_in[5];
    const float* bv = (const float*)d_in[6];
    float* out = (float*)d_out;

    unsigned short* ws = (unsigned short*)d_ws;
    unsigned short* x_hi   = ws;                 // 4,194,304
    unsigned short* x_lo   = ws + 4194304;       // 4,194,304
    unsigned short* q_hi   = ws + 8388608;       //   524,288
    unsigned short* q_lo   = ws + 8912896;       //   524,288
    unsigned short* k_hi   = ws + 9437184;       //   524,288
    unsigned short* k_lo   = ws + 9961472;       //   524,288
    unsigned short* v_frag = ws + 10485760;      // 4,194,304  -> ~28 MB total

    cast_kernel<<<dim3(256, BATCH), 256, 0, stream>>>(x, x_hi, x_lo);
    proj_kernel<<<dim3(64, 5, BATCH), 256, 0, stream>>>(x_hi, x_lo, Wq, bq, Wk, bk, Wv, bv,
                                                        q_hi, q_lo, k_hi, k_lo, v_frag);
    attn_kernel<<<dim3(128, BATCH), 1024, 0, stream>>>(q_hi, q_lo, k_hi, k_lo, v_frag, x, out);
}